// Round 2
// baseline (550.834 us; speedup 1.0000x reference)
//
#include <hip/hip_runtime.h>
#include <hip/hip_bf16.h>

#define B_ 2
#define T_ 2048
#define E_ 1024
#define H_ 16
#define D_ 64
#define F_ 3072
#define M_ 4096  // B_*T_

typedef __attribute__((ext_vector_type(8))) short short8v;
typedef __attribute__((ext_vector_type(4))) short short4v;
typedef __attribute__((ext_vector_type(4))) float float4v;

__device__ __forceinline__ ushort f2bf(float f) {
    union { float f; unsigned u; } v; v.f = f;
    unsigned u = v.u;
    unsigned r = (u + 0x7FFFu + ((u >> 16) & 1u)) >> 16;
    return (ushort)r;
}

// ---- fp32 -> bf16 conversion, 4 elems per thread ----
__global__ void cvt_kernel(const float* __restrict__ in, ushort* __restrict__ out, int n4) {
    int i = blockIdx.x * blockDim.x + threadIdx.x;
    if (i >= n4) return;
    float4 v = ((const float4*)in)[i];
    ushort4 o;
    o.x = f2bf(v.x); o.y = f2bf(v.y); o.z = f2bf(v.z); o.w = f2bf(v.w);
    ((ushort4*)out)[i] = o;
}

// ---- GEMM: C[M][N] = A[M][K] * Bt[N][K]^T  (both bf16, K multiple of 32) ----
// MODE 0: qkv epilogue (bias, q-scale, scatter: q,k -> [B][H][T][D]; v -> [B][H][D][T])
// MODE 1: fp32 out epilogue (bias)
template <int MODE>
__global__ __launch_bounds__(256) void gemm_bt(const ushort* __restrict__ A,
                                               const ushort* __restrict__ Bt,
                                               const float* __restrict__ bias,
                                               void* __restrict__ Cout,
                                               int Ndim, int K) {
    int lane = threadIdx.x & 63;
    int w = threadIdx.x >> 6;
    int wr = w >> 1, wc = w & 1;
    int mb = blockIdx.x * 128 + wr * 64;
    int nb = blockIdx.y * 128 + wc * 64;
    int r15 = lane & 15, g = lane >> 4;

    const ushort* Abase = A + (size_t)(mb + r15) * K + g * 8;
    const ushort* Bbase = Bt + (size_t)(nb + r15) * K + g * 8;

    float4v acc[4][4] = {};
    for (int k0 = 0; k0 < K; k0 += 32) {
        short8v af[4], bf[4];
#pragma unroll
        for (int r = 0; r < 4; ++r)
            af[r] = *(const short8v*)(Abase + (size_t)r * 16 * K + k0);
#pragma unroll
        for (int c = 0; c < 4; ++c)
            bf[c] = *(const short8v*)(Bbase + (size_t)c * 16 * K + k0);
#pragma unroll
        for (int r = 0; r < 4; ++r)
#pragma unroll
            for (int c = 0; c < 4; ++c)
                acc[r][c] = __builtin_amdgcn_mfma_f32_16x16x32_bf16(af[r], bf[c], acc[r][c], 0, 0, 0);
    }

    if (MODE == 0) {
        ushort* qkv = (ushort*)Cout;
#pragma unroll
        for (int r = 0; r < 4; ++r)
#pragma unroll
            for (int c = 0; c < 4; ++c)
#pragma unroll
                for (int ri = 0; ri < 4; ++ri) {
                    int m = mb + r * 16 + g * 4 + ri;
                    int n = nb + c * 16 + r15;
                    float v = acc[r][c][ri] + bias[n];
                    int which = n >> 10;          // 0:q 1:k 2:v
                    int e = n & 1023;
                    if (which == 0) v *= 0.125f;  // D^-0.5
                    int h = e >> 6, d = e & 63;
                    int b = m >> 11, t = m & 2047;
                    size_t addr;
                    if (which == 2)  // V transposed: [B][H][D][T]
                        addr = (size_t)2 * M_ * E_ +
                               ((size_t)(b * H_ + h) * D_ + d) * T_ + t;
                    else
                        addr = (size_t)which * M_ * E_ +
                               ((size_t)(b * H_ + h) * T_ + t) * D_ + d;
                    qkv[addr] = f2bf(v);
                }
    } else {
        float* out = (float*)Cout;
#pragma unroll
        for (int r = 0; r < 4; ++r)
#pragma unroll
            for (int c = 0; c < 4; ++c)
#pragma unroll
                for (int ri = 0; ri < 4; ++ri) {
                    int m = mb + r * 16 + g * 4 + ri;
                    int n = nb + c * 16 + r15;
                    out[(size_t)m * Ndim + n] = acc[r][c][ri] + bias[n];
                }
    }
}

// ---- flash attention: 1 block = (head, 64 q-rows); wave = 16 q-rows ----
// S^T = mfma(K_frag, Q_frag): C-layout == A-layout of P for the PV mfma.
// KVBLK = 32; PV uses permuted-k 16x16x32 (slots 0..3 = tile0 keys g*4+j,
// slots 4..7 = tile1 keys 16+g*4+j), consistent on A (P) and B (V^T).
__global__ __launch_bounds__(256) void attn_kernel(const ushort* __restrict__ qkv,
                                                   ushort* __restrict__ Ob) {
    int lane = threadIdx.x & 63;
    int w = threadIdx.x >> 6;
    int bh = blockIdx.x >> 5;   // b*H + h
    int qt = blockIdx.x & 31;
    int r15 = lane & 15, g = lane >> 4;
    int qb = qt * 64 + w * 16;

    const ushort* Qh = qkv + (size_t)bh * T_ * D_;
    const ushort* Kh = qkv + (size_t)M_ * E_ + (size_t)bh * T_ * D_;
    const ushort* Vt = qkv + (size_t)2 * M_ * E_ + (size_t)bh * D_ * T_;  // [D][T]

    const ushort* Qrow = Qh + (size_t)(qb + r15) * D_ + g * 8;
    short8v qf0 = *(const short8v*)(Qrow);
    short8v qf1 = *(const short8v*)(Qrow + 32);

    float4v oacc[4] = {};
    float m_run = -1e30f, l_run = 0.f;

    for (int kt = 0; kt < T_ / 32; ++kt) {
        int kb = kt * 32;
        const ushort* Krow = Kh + (size_t)(kb + r15) * D_ + g * 8;
        short8v ka0 = *(const short8v*)(Krow);
        short8v ka1 = *(const short8v*)(Krow + 32);
        short8v kb0 = *(const short8v*)(Krow + 16 * D_);
        short8v kb1 = *(const short8v*)(Krow + 16 * D_ + 32);

        float4v st0 = {0.f, 0.f, 0.f, 0.f};
        float4v st1 = {0.f, 0.f, 0.f, 0.f};
        st0 = __builtin_amdgcn_mfma_f32_16x16x32_bf16(ka0, qf0, st0, 0, 0, 0);
        st0 = __builtin_amdgcn_mfma_f32_16x16x32_bf16(ka1, qf1, st0, 0, 0, 0);
        st1 = __builtin_amdgcn_mfma_f32_16x16x32_bf16(kb0, qf0, st1, 0, 0, 0);
        st1 = __builtin_amdgcn_mfma_f32_16x16x32_bf16(kb1, qf1, st1, 0, 0, 0);
        // lane holds S^T[key = kb + 16*tile + g*4 + ri][q = r15]

        float tmax = fmaxf(fmaxf(fmaxf(st0[0], st0[1]), fmaxf(st0[2], st0[3])),
                           fmaxf(fmaxf(st1[0], st1[1]), fmaxf(st1[2], st1[3])));
        tmax = fmaxf(tmax, __shfl_xor(tmax, 16));
        tmax = fmaxf(tmax, __shfl_xor(tmax, 32));

        // defer-max: only rescale when some row's max grew by > 8
        if (!__all(tmax - m_run <= 8.0f)) {
            float mnew = fmaxf(m_run, tmax);
            float corr = __expf(m_run - mnew);
            float c0 = __shfl(corr, g * 4 + 0);
            float c1 = __shfl(corr, g * 4 + 1);
            float c2 = __shfl(corr, g * 4 + 2);
            float c3 = __shfl(corr, g * 4 + 3);
#pragma unroll
            for (int c = 0; c < 4; ++c) {
                oacc[c][0] *= c0; oacc[c][1] *= c1;
                oacc[c][2] *= c2; oacc[c][3] *= c3;
            }
            l_run *= corr;
            m_run = mnew;
        }

        float p0 = __expf(st0[0] - m_run), p1 = __expf(st0[1] - m_run);
        float p2 = __expf(st0[2] - m_run), p3 = __expf(st0[3] - m_run);
        float p4 = __expf(st1[0] - m_run), p5 = __expf(st1[1] - m_run);
        float p6 = __expf(st1[2] - m_run), p7 = __expf(st1[3] - m_run);
        float ts = ((p0 + p1) + (p2 + p3)) + ((p4 + p5) + (p6 + p7));
        ts += __shfl_xor(ts, 16);
        ts += __shfl_xor(ts, 32);
        l_run += ts;

        short8v pf;
        pf[0] = (short)f2bf(p0); pf[1] = (short)f2bf(p1);
        pf[2] = (short)f2bf(p2); pf[3] = (short)f2bf(p3);
        pf[4] = (short)f2bf(p4); pf[5] = (short)f2bf(p5);
        pf[6] = (short)f2bf(p6); pf[7] = (short)f2bf(p7);

        const ushort* vb = Vt + kb + g * 4;
#pragma unroll
        for (int c = 0; c < 4; ++c) {
            const ushort* vp = vb + (size_t)(c * 16 + r15) * T_;
            short4v v0 = *(const short4v*)(vp);        // tile0 keys g*4+0..3
            short4v v1 = *(const short4v*)(vp + 16);   // tile1 keys 16+g*4+0..3
            short8v vf;
            vf[0] = v0[0]; vf[1] = v0[1]; vf[2] = v0[2]; vf[3] = v0[3];
            vf[4] = v1[0]; vf[5] = v1[1]; vf[6] = v1[2]; vf[7] = v1[3];
            oacc[c] = __builtin_amdgcn_mfma_f32_16x16x32_bf16(pf, vf, oacc[c], 0, 0, 0);
        }
    }

    float s0 = __shfl(l_run, g * 4 + 0);
    float s1 = __shfl(l_run, g * 4 + 1);
    float s2 = __shfl(l_run, g * 4 + 2);
    float s3 = __shfl(l_run, g * 4 + 3);
    float i0 = 1.f / s0, i1 = 1.f / s1, i2 = 1.f / s2, i3 = 1.f / s3;

    int b = bh >> 4, h = bh & 15;
#pragma unroll
    for (int c = 0; c < 4; ++c) {
        size_t base = ((size_t)b * T_ + qb + g * 4) * E_ + h * 64 + c * 16 + r15;
        Ob[base]          = f2bf(oacc[c][0] * i0);
        Ob[base + E_]     = f2bf(oacc[c][1] * i1);
        Ob[base + 2 * E_] = f2bf(oacc[c][2] * i2);
        Ob[base + 3 * E_] = f2bf(oacc[c][3] * i3);
    }
}

extern "C" void kernel_launch(void* const* d_in, const int* in_sizes, int n_in,
                              void* d_out, int out_size, void* d_ws, size_t ws_size,
                              hipStream_t stream) {
    const float* query = (const float*)d_in[0];
    const float* Wqkv  = (const float*)d_in[1];
    const float* bqkv  = (const float*)d_in[2];
    const float* Wo    = (const float*)d_in[3];
    const float* bo    = (const float*)d_in[4];
    float* out = (float*)d_out;

    // workspace layout (bf16 elements): total 24M elems = 48 MB
    ushort* Xb    = (ushort*)d_ws;                       // M_*E_   (8 MB)
    ushort* Wqkvb = Xb + (size_t)M_ * E_;                // F_*E_   (6 MB)
    ushort* Wob   = Wqkvb + (size_t)F_ * E_;             // E_*E_   (2 MB)
    ushort* QKVb  = Wob + (size_t)E_ * E_;               // 3*M_*E_ (24 MB)
    ushort* Ob    = QKVb + (size_t)3 * M_ * E_;          // M_*E_   (8 MB), [B*T][E]

    cvt_kernel<<<(M_ * E_ / 4 + 255) / 256, 256, 0, stream>>>(query, Xb, M_ * E_ / 4);
    cvt_kernel<<<(F_ * E_ / 4 + 255) / 256, 256, 0, stream>>>(Wqkv, Wqkvb, F_ * E_ / 4);
    cvt_kernel<<<(E_ * E_ / 4 + 255) / 256, 256, 0, stream>>>(Wo, Wob, E_ * E_ / 4);

    gemm_bt<0><<<dim3(M_ / 128, F_ / 128), 256, 0, stream>>>(Xb, Wqkvb, bqkv, QKVb, F_, E_);
    attn_kernel<<<(B_ * H_) * (T_ / 64), 256, 0, stream>>>(QKVb, Ob);
    gemm_bt<1><<<dim3(M_ / 128, E_ / 128), 256, 0, stream>>>(Ob, Wob, bo, out, E_, E_);
}

// Round 3
// 333.208 us; speedup vs baseline: 1.6531x; 1.6531x over previous
//
#include <hip/hip_runtime.h>
#include <hip/hip_bf16.h>

#define B_ 2
#define T_ 2048
#define E_ 1024
#define H_ 16
#define D_ 64
#define F_ 3072
#define M_ 4096        // B_*T_
#define VT_STRIDE 2080 // padded V^T row stride (breaks 4KB L1-set aliasing)

typedef __attribute__((ext_vector_type(8))) short short8v;
typedef __attribute__((ext_vector_type(4))) short short4v;
typedef __attribute__((ext_vector_type(4))) float float4v;

__device__ __forceinline__ ushort f2bf(float f) {
    union { float f; unsigned u; } v; v.f = f;
    unsigned u = v.u;
    unsigned r = (u + 0x7FFFu + ((u >> 16) & 1u)) >> 16;
    return (ushort)r;
}

// ---- fp32 -> bf16 conversion, 4 elems per thread ----
__global__ void cvt_kernel(const float* __restrict__ in, ushort* __restrict__ out, int n4) {
    int i = blockIdx.x * blockDim.x + threadIdx.x;
    if (i >= n4) return;
    float4 v = ((const float4*)in)[i];
    ushort4 o;
    o.x = f2bf(v.x); o.y = f2bf(v.y); o.z = f2bf(v.z); o.w = f2bf(v.w);
    ((ushort4*)out)[i] = o;
}

// ---- GEMM: C[M][N] = A[M][K] * Bt[N][K]^T  (both bf16, K multiple of 32) ----
// MODE 0: qkv epilogue (bias, q-scale; q,k -> [B][H][T][D]; v -> [B][H][D][VT_STRIDE])
// MODE 1: fp32 out epilogue (bias)
template <int MODE>
__global__ __launch_bounds__(256) void gemm_bt(const ushort* __restrict__ A,
                                               const ushort* __restrict__ Bt,
                                               const float* __restrict__ bias,
                                               void* __restrict__ Cout,
                                               int Ndim, int K) {
    int lane = threadIdx.x & 63;
    int w = threadIdx.x >> 6;
    int wr = w >> 1, wc = w & 1;
    int mb = blockIdx.x * 128 + wr * 64;
    int nb = blockIdx.y * 128 + wc * 64;
    int r15 = lane & 15, g = lane >> 4;

    const ushort* Abase = A + (size_t)(mb + r15) * K + g * 8;
    const ushort* Bbase = Bt + (size_t)(nb + r15) * K + g * 8;

    float4v acc[4][4] = {};
    for (int k0 = 0; k0 < K; k0 += 32) {
        short8v af[4], bf[4];
#pragma unroll
        for (int r = 0; r < 4; ++r)
            af[r] = *(const short8v*)(Abase + (size_t)r * 16 * K + k0);
#pragma unroll
        for (int c = 0; c < 4; ++c)
            bf[c] = *(const short8v*)(Bbase + (size_t)c * 16 * K + k0);
#pragma unroll
        for (int r = 0; r < 4; ++r)
#pragma unroll
            for (int c = 0; c < 4; ++c)
                acc[r][c] = __builtin_amdgcn_mfma_f32_16x16x32_bf16(af[r], bf[c], acc[r][c], 0, 0, 0);
    }

    if (MODE == 0) {
        ushort* qkv = (ushort*)Cout;
#pragma unroll
        for (int r = 0; r < 4; ++r)
#pragma unroll
            for (int c = 0; c < 4; ++c)
#pragma unroll
                for (int ri = 0; ri < 4; ++ri) {
                    int m = mb + r * 16 + g * 4 + ri;
                    int n = nb + c * 16 + r15;
                    float v = acc[r][c][ri] + bias[n];
                    int which = n >> 10;          // 0:q 1:k 2:v
                    int e = n & 1023;
                    if (which == 0) v *= 0.125f;  // D^-0.5
                    int h = e >> 6, d = e & 63;
                    int b = m >> 11, t = m & 2047;
                    size_t addr;
                    if (which == 2)  // V transposed + padded: [B][H][D][VT_STRIDE]
                        addr = (size_t)2 * M_ * E_ +
                               ((size_t)(b * H_ + h) * D_ + d) * VT_STRIDE + t;
                    else
                        addr = (size_t)which * M_ * E_ +
                               ((size_t)(b * H_ + h) * T_ + t) * D_ + d;
                    qkv[addr] = f2bf(v);
                }
    } else {
        float* out = (float*)Cout;
#pragma unroll
        for (int r = 0; r < 4; ++r)
#pragma unroll
            for (int c = 0; c < 4; ++c)
#pragma unroll
                for (int ri = 0; ri < 4; ++ri) {
                    int m = mb + r * 16 + g * 4 + ri;
                    int n = nb + c * 16 + r15;
                    out[(size_t)m * Ndim + n] = acc[r][c][ri] + bias[n];
                }
    }
}

// ---- flash attention: 1 block = (head, 128 q-rows); wave = 32 q-rows (2 subtiles) ----
// S^T = mfma(K_frag, Q_frag): C-layout == A-layout of P for the PV mfma.
// KVBLK = 32; K-frags and V-frags shared across the 2 q-subtiles.
__global__ __launch_bounds__(256) void attn_kernel(const ushort* __restrict__ qkv,
                                                   ushort* __restrict__ Ob) {
    int lane = threadIdx.x & 63;
    int w = threadIdx.x >> 6;
    int bh = blockIdx.x >> 4;   // b*H + h  (16 q-tiles per head)
    int qt = blockIdx.x & 15;
    int r15 = lane & 15, g = lane >> 4;
    int qb = qt * 128 + w * 32;

    const ushort* Qh = qkv + (size_t)bh * T_ * D_;
    const ushort* Kh = qkv + (size_t)M_ * E_ + (size_t)bh * T_ * D_;
    const ushort* Vt = qkv + (size_t)2 * M_ * E_ + (size_t)bh * D_ * VT_STRIDE;

    const ushort* QrowA = Qh + (size_t)(qb + r15) * D_ + g * 8;
    short8v qfA0 = *(const short8v*)(QrowA);
    short8v qfA1 = *(const short8v*)(QrowA + 32);
    short8v qfB0 = *(const short8v*)(QrowA + 16 * D_);
    short8v qfB1 = *(const short8v*)(QrowA + 16 * D_ + 32);

    float4v oaccA[4] = {}, oaccB[4] = {};
    float mA = -1e30f, lA = 0.f;
    float mB = -1e30f, lB = 0.f;

    auto softmax_step = [&](float4v& s0, float4v& s1, float& m_run, float& l_run,
                            float4v* oacc, short8v& pf) {
        float tmax = fmaxf(fmaxf(fmaxf(s0[0], s0[1]), fmaxf(s0[2], s0[3])),
                           fmaxf(fmaxf(s1[0], s1[1]), fmaxf(s1[2], s1[3])));
        tmax = fmaxf(tmax, __shfl_xor(tmax, 16));
        tmax = fmaxf(tmax, __shfl_xor(tmax, 32));
        if (!__all(tmax - m_run <= 8.0f)) {   // defer-max (T13)
            float mnew = fmaxf(m_run, tmax);
            float corr = __expf(m_run - mnew);
            float c0 = __shfl(corr, g * 4 + 0);
            float c1 = __shfl(corr, g * 4 + 1);
            float c2 = __shfl(corr, g * 4 + 2);
            float c3 = __shfl(corr, g * 4 + 3);
#pragma unroll
            for (int c = 0; c < 4; ++c) {
                oacc[c][0] *= c0; oacc[c][1] *= c1;
                oacc[c][2] *= c2; oacc[c][3] *= c3;
            }
            l_run *= corr;
            m_run = mnew;
        }
        float p0 = __expf(s0[0] - m_run), p1 = __expf(s0[1] - m_run);
        float p2 = __expf(s0[2] - m_run), p3 = __expf(s0[3] - m_run);
        float p4 = __expf(s1[0] - m_run), p5 = __expf(s1[1] - m_run);
        float p6 = __expf(s1[2] - m_run), p7 = __expf(s1[3] - m_run);
        float ts = ((p0 + p1) + (p2 + p3)) + ((p4 + p5) + (p6 + p7));
        ts += __shfl_xor(ts, 16);
        ts += __shfl_xor(ts, 32);
        l_run += ts;
        pf[0] = (short)f2bf(p0); pf[1] = (short)f2bf(p1);
        pf[2] = (short)f2bf(p2); pf[3] = (short)f2bf(p3);
        pf[4] = (short)f2bf(p4); pf[5] = (short)f2bf(p5);
        pf[6] = (short)f2bf(p6); pf[7] = (short)f2bf(p7);
    };

    for (int kt = 0; kt < T_ / 32; ++kt) {
        int kb = kt * 32;
        const ushort* Krow = Kh + (size_t)(kb + r15) * D_ + g * 8;
        short8v k00 = *(const short8v*)(Krow);
        short8v k01 = *(const short8v*)(Krow + 32);
        short8v k10 = *(const short8v*)(Krow + 16 * D_);
        short8v k11 = *(const short8v*)(Krow + 16 * D_ + 32);

        float4v stA0 = {}, stA1 = {}, stB0 = {}, stB1 = {};
        stA0 = __builtin_amdgcn_mfma_f32_16x16x32_bf16(k00, qfA0, stA0, 0, 0, 0);
        stA0 = __builtin_amdgcn_mfma_f32_16x16x32_bf16(k01, qfA1, stA0, 0, 0, 0);
        stA1 = __builtin_amdgcn_mfma_f32_16x16x32_bf16(k10, qfA0, stA1, 0, 0, 0);
        stA1 = __builtin_amdgcn_mfma_f32_16x16x32_bf16(k11, qfA1, stA1, 0, 0, 0);
        stB0 = __builtin_amdgcn_mfma_f32_16x16x32_bf16(k00, qfB0, stB0, 0, 0, 0);
        stB0 = __builtin_amdgcn_mfma_f32_16x16x32_bf16(k01, qfB1, stB0, 0, 0, 0);
        stB1 = __builtin_amdgcn_mfma_f32_16x16x32_bf16(k10, qfB0, stB1, 0, 0, 0);
        stB1 = __builtin_amdgcn_mfma_f32_16x16x32_bf16(k11, qfB1, stB1, 0, 0, 0);
        // lane holds S^T[key = kb + 16*tile + g*4 + ri][q = r15] per subtile

        short8v pfA, pfB;
        softmax_step(stA0, stA1, mA, lA, oaccA, pfA);
        softmax_step(stB0, stB1, mB, lB, oaccB, pfB);

        const ushort* vbase = Vt + kb + g * 4;
#pragma unroll
        for (int c = 0; c < 4; ++c) {
            const ushort* vp = vbase + (size_t)(c * 16 + r15) * VT_STRIDE;
            short4v v0 = *(const short4v*)(vp);        // tile0 keys g*4+0..3
            short4v v1 = *(const short4v*)(vp + 16);   // tile1 keys 16+g*4+0..3
            short8v vf;
            vf[0] = v0[0]; vf[1] = v0[1]; vf[2] = v0[2]; vf[3] = v0[3];
            vf[4] = v1[0]; vf[5] = v1[1]; vf[6] = v1[2]; vf[7] = v1[3];
            oaccA[c] = __builtin_amdgcn_mfma_f32_16x16x32_bf16(pfA, vf, oaccA[c], 0, 0, 0);
            oaccB[c] = __builtin_amdgcn_mfma_f32_16x16x32_bf16(pfB, vf, oaccB[c], 0, 0, 0);
        }
    }

    int b = bh >> 4, h = bh & 15;
    {
        float s0 = __shfl(lA, g * 4 + 0), s1 = __shfl(lA, g * 4 + 1);
        float s2 = __shfl(lA, g * 4 + 2), s3 = __shfl(lA, g * 4 + 3);
        float i0 = 1.f / s0, i1 = 1.f / s1, i2 = 1.f / s2, i3 = 1.f / s3;
#pragma unroll
        for (int c = 0; c < 4; ++c) {
            size_t base = ((size_t)b * T_ + qb + g * 4) * E_ + h * 64 + c * 16 + r15;
            Ob[base]          = f2bf(oaccA[c][0] * i0);
            Ob[base + E_]     = f2bf(oaccA[c][1] * i1);
            Ob[base + 2 * E_] = f2bf(oaccA[c][2] * i2);
            Ob[base + 3 * E_] = f2bf(oaccA[c][3] * i3);
        }
    }
    {
        float s0 = __shfl(lB, g * 4 + 0), s1 = __shfl(lB, g * 4 + 1);
        float s2 = __shfl(lB, g * 4 + 2), s3 = __shfl(lB, g * 4 + 3);
        float i0 = 1.f / s0, i1 = 1.f / s1, i2 = 1.f / s2, i3 = 1.f / s3;
#pragma unroll
        for (int c = 0; c < 4; ++c) {
            size_t base = ((size_t)b * T_ + qb + 16 + g * 4) * E_ + h * 64 + c * 16 + r15;
            Ob[base]          = f2bf(oaccB[c][0] * i0);
            Ob[base + E_]     = f2bf(oaccB[c][1] * i1);
            Ob[base + 2 * E_] = f2bf(oaccB[c][2] * i2);
            Ob[base + 3 * E_] = f2bf(oaccB[c][3] * i3);
        }
    }
}

extern "C" void kernel_launch(void* const* d_in, const int* in_sizes, int n_in,
                              void* d_out, int out_size, void* d_ws, size_t ws_size,
                              hipStream_t stream) {
    const float* query = (const float*)d_in[0];
    const float* Wqkv  = (const float*)d_in[1];
    const float* bqkv  = (const float*)d_in[2];
    const float* Wo    = (const float*)d_in[3];
    const float* bo    = (const float*)d_in[4];
    float* out = (float*)d_out;

    // workspace (bf16 elems), ~42 MB total. Ob aliases Xb (Xb dead after GEMM1).
    ushort* Xb    = (ushort*)d_ws;                        // M_*E_ (8 MB)
    ushort* Wqkvb = Xb + (size_t)M_ * E_;                 // F_*E_ (6 MB)
    ushort* Wob   = Wqkvb + (size_t)F_ * E_;              // E_*E_ (2 MB)
    ushort* QKVb  = Wob + (size_t)E_ * E_;                // 2*M_*E_ + B*H*D*VT_STRIDE
    ushort* Ob    = Xb;                                   // alias: [B*T][E]

    cvt_kernel<<<(M_ * E_ / 4 + 255) / 256, 256, 0, stream>>>(query, Xb, M_ * E_ / 4);
    cvt_kernel<<<(F_ * E_ / 4 + 255) / 256, 256, 0, stream>>>(Wqkv, Wqkvb, F_ * E_ / 4);
    cvt_kernel<<<(E_ * E_ / 4 + 255) / 256, 256, 0, stream>>>(Wo, Wob, E_ * E_ / 4);

    gemm_bt<0><<<dim3(M_ / 128, F_ / 128), 256, 0, stream>>>(Xb, Wqkvb, bqkv, QKVb, F_, E_);
    attn_kernel<<<(B_ * H_) * (T_ / 128), 256, 0, stream>>>(QKVb, Ob);
    gemm_bt<1><<<dim3(M_ / 128, E_ / 128), 256, 0, stream>>>(Ob, Wob, bo, out, E_, E_);
}